// Round 5
// baseline (416.024 us; speedup 1.0000x reference)
//
#include <hip/hip_runtime.h>
#include <hip/hip_bf16.h>

// HQQ 4-bit linear: out = x @ dequant(W_q)^T + bias
// M=B*S=4096, K=4096, N=4096, GROUP=128. Output FP32.
//
// Round 11: FULL FUSION. The prepass (x fp32->bf16, Wq->bf16 dequant) is
// deleted; both transforms happen inside the GEMM's staging path:
//   global_load (fp32 / int32) -> regs -> transform -> ds_write_b128.
// LDS layout is byte-identical to rounds 9/10 (pre-swizzled source rows,
// linear destination slots); readers unchanged. ds_writes are conflict-free
// (consecutive lanes -> consecutive 16B).
// Schedule: 4 phases/K-tile, ONE barrier per phase, with s_waitcnt
// lgkmcnt(0) before every barrier -> all LDS reads AND writes of phase p
// complete before any wave enters p+1 (airtight lag-1 staging, no round-9
// race, no round-10 double barrier). Staged global loads are gated by
// counted vmcnt (4/8/4/4 per phase; region-granular so intra-phase compiler
// reordering cannot break the counts; never drains in the main loop).
// Scale/zero for tile T+2's group are loaded at P1 and consumed at P4/next-P2.

typedef __bf16 bf16x8 __attribute__((ext_vector_type(8)));
typedef float f32x4 __attribute__((ext_vector_type(4)));

static __device__ __forceinline__ int pack_bf16x2(float a, float b) {
    __hip_bfloat162 p = __float22bfloat162_rn(make_float2(a, b));
    int r;
    __builtin_memcpy(&r, &p, 4);
    return r;
}

struct ARegs { float4 v[2][2]; };   // [unit l][chunk of 4 fp32]
struct BRegs { int4   q[2][2]; };   // [unit l][chunk of 4 int32]

// ---------------- fused GEMM: 256x256 tile, 4-phase/K-tile ------------------
// 512 threads = 8 waves (2M x 4N); wave owns 128x64 of C = 8x4 fragments of
// 16x16x32 MFMA. LDS: [2 buf][2 khalf] subtiles of 256x32 bf16 (16KB) per
// operand, 128 KiB total (1 block/CU).
__global__ __launch_bounds__(512, 2) void hqq_gemm256_fused(
    const float* __restrict__ X,      // fp32 [M,K]
    const int*   __restrict__ Wq,     // int32 [N,K], values 0..15
    const float* __restrict__ scale,  // fp32 [N,G]
    const float* __restrict__ zero,   // fp32 [N,G]
    const float* __restrict__ bias,   // fp32 [N]
    float*       __restrict__ C,      // fp32 [M,N]
    int M, int N, int K, int G)
{
    __shared__ unsigned short ldsA[2][2][8192];   // [buf][kh][256x32 packed]
    __shared__ unsigned short ldsB[2][2][8192];

    const int tid  = threadIdx.x;
    const int lane = tid & 63;
    const int wave = tid >> 6;     // 0..7
    const int wm   = wave >> 2;    // 0..1  (M half)
    const int wn   = wave & 3;     // 0..3  (N quarter)

    // XCD-bijective swizzle (nwg % 8 == 0 guaranteed by launcher).
    const int nwg  = (N >> 8) * (M >> 8);
    const int cpx  = nwg >> 3;
    const int bid  = blockIdx.x;
    const int wgid = (bid & 7) * cpx + (bid >> 3);
    const int bx   = wgid % (N >> 8);
    const int by   = wgid / (N >> 8);
    const int blockN0 = bx << 8;
    const int blockM0 = by << 8;

    // staging maps: slot s = l*512+tid -> phys row R=s>>3, slot j=s&7.
    // Source row is PRE-SWIZZLED (ju = j ^ (R&7)); LDS destination is LINEAR
    // (consecutive lanes -> consecutive 16B => conflict-free ds_write_b128).
    // Final layout identical to rounds 9/10; readers unchanged.
    long long gSrcA[2], gSrcB[2];
    int nIdx[2], wrElem[2];
#pragma unroll
    for (int l = 0; l < 2; ++l) {
        const int s  = l * 512 + tid;
        const int R  = s >> 3;
        const int j  = s & 7;
        const int ju = j ^ (R & 7);
        const int r  = 2 * R + (ju >> 2);
        const int cc = ju & 3;
        gSrcA[l]  = (long long)(blockM0 + r) * K + cc * 8;
        gSrcB[l]  = (long long)(blockN0 + r) * K + cc * 8;
        nIdx[l]   = blockN0 + r;
        wrElem[l] = s * 8;
    }

    // fragment read offsets (elements within a 16KB subtile) -- verified.
    const int row16 = lane & 15;
    const int quad  = lane >> 4;
    int offA[8], offB[4];
#pragma unroll
    for (int m = 0; m < 8; ++m) {
        const int r = wm * 128 + m * 16 + row16;
        const int R = r >> 1;
        const int j = (((r & 1) << 2) | quad) ^ (R & 7);
        offA[m] = R * 64 + j * 8;
    }
#pragma unroll
    for (int n = 0; n < 4; ++n) {
        const int r = wn * 64 + n * 16 + row16;
        const int R = r >> 1;
        const int j = (((r & 1) << 2) | quad) ^ (R & 7);
        offB[n] = R * 64 + j * 8;
    }

    f32x4 acc[8][4];
#pragma unroll
    for (int m = 0; m < 8; ++m)
#pragma unroll
        for (int n = 0; n < 4; ++n)
            acc[m][n] = (f32x4){0.f, 0.f, 0.f, 0.f};

#define LOAD_A(dst_, T_, KH_)                                                 \
    do {                                                                      \
        const long long ko_ = (long long)(T_) * 64 + (KH_) * 32;              \
        _Pragma("unroll")                                                     \
        for (int l = 0; l < 2; ++l) {                                         \
            const float* p_ = X + gSrcA[l] + ko_;                             \
            dst_.v[l][0] = *(const float4*)p_;                                \
            dst_.v[l][1] = *(const float4*)(p_ + 4);                          \
        }                                                                     \
    } while (0)

#define LOAD_B(dst_, T_, KH_)                                                 \
    do {                                                                      \
        const long long ko_ = (long long)(T_) * 64 + (KH_) * 32;              \
        _Pragma("unroll")                                                     \
        for (int l = 0; l < 2; ++l) {                                         \
            const int* p_ = Wq + gSrcB[l] + ko_;                              \
            dst_.q[l][0] = *(const int4*)p_;                                  \
            dst_.q[l][1] = *(const int4*)(p_ + 4);                           \
        }                                                                     \
    } while (0)

#define WRITE_A(buf_, kh_, rgs_)                                              \
    do {                                                                      \
        _Pragma("unroll")                                                     \
        for (int l = 0; l < 2; ++l) {                                         \
            int4 d_;                                                          \
            d_.x = pack_bf16x2(rgs_.v[l][0].x, rgs_.v[l][0].y);               \
            d_.y = pack_bf16x2(rgs_.v[l][0].z, rgs_.v[l][0].w);               \
            d_.z = pack_bf16x2(rgs_.v[l][1].x, rgs_.v[l][1].y);               \
            d_.w = pack_bf16x2(rgs_.v[l][1].z, rgs_.v[l][1].w);               \
            *(int4*)&ldsA[buf_][kh_][wrElem[l]] = d_;                         \
        }                                                                     \
    } while (0)

#define WRITE_B(buf_, kh_, rgs_, s0_, z0_, s1_, z1_)                          \
    do {                                                                      \
        {                                                                     \
            const float s_ = (s0_), mz_ = -(z0_) * (s0_);                     \
            const int4 q0_ = rgs_.q[0][0], q1_ = rgs_.q[0][1];                \
            int4 d_;                                                          \
            d_.x = pack_bf16x2((float)q0_.x * s_ + mz_, (float)q0_.y * s_ + mz_); \
            d_.y = pack_bf16x2((float)q0_.z * s_ + mz_, (float)q0_.w * s_ + mz_); \
            d_.z = pack_bf16x2((float)q1_.x * s_ + mz_, (float)q1_.y * s_ + mz_); \
            d_.w = pack_bf16x2((float)q1_.z * s_ + mz_, (float)q1_.w * s_ + mz_); \
            *(int4*)&ldsB[buf_][kh_][wrElem[0]] = d_;                         \
        }                                                                     \
        {                                                                     \
            const float s_ = (s1_), mz_ = -(z1_) * (s1_);                     \
            const int4 q0_ = rgs_.q[1][0], q1_ = rgs_.q[1][1];                \
            int4 d_;                                                          \
            d_.x = pack_bf16x2((float)q0_.x * s_ + mz_, (float)q0_.y * s_ + mz_); \
            d_.y = pack_bf16x2((float)q0_.z * s_ + mz_, (float)q0_.w * s_ + mz_); \
            d_.z = pack_bf16x2((float)q1_.x * s_ + mz_, (float)q1_.y * s_ + mz_); \
            d_.w = pack_bf16x2((float)q1_.z * s_ + mz_, (float)q1_.w * s_ + mz_); \
            *(int4*)&ldsB[buf_][kh_][wrElem[1]] = d_;                         \
        }                                                                     \
    } while (0)

#define READ_BV(c_, kk_)                                                      \
    bv0 = *(const bf16x8*)&ldsB[c_][kk_][offB[0]];                            \
    bv1 = *(const bf16x8*)&ldsB[c_][kk_][offB[1]];                            \
    bv2 = *(const bf16x8*)&ldsB[c_][kk_][offB[2]];                            \
    bv3 = *(const bf16x8*)&ldsB[c_][kk_][offB[3]];

#define READ_AV(c_, kk_, mh_)                                                 \
    av0 = *(const bf16x8*)&ldsA[c_][kk_][offA[(mh_) * 4 + 0]];                \
    av1 = *(const bf16x8*)&ldsA[c_][kk_][offA[(mh_) * 4 + 1]];                \
    av2 = *(const bf16x8*)&ldsA[c_][kk_][offA[(mh_) * 4 + 2]];                \
    av3 = *(const bf16x8*)&ldsA[c_][kk_][offA[(mh_) * 4 + 3]];

#define MFROW(mi_, av_)                                                       \
    acc[mi_][0] = __builtin_amdgcn_mfma_f32_16x16x32_bf16(av_, bv0, acc[mi_][0], 0, 0, 0); \
    acc[mi_][1] = __builtin_amdgcn_mfma_f32_16x16x32_bf16(av_, bv1, acc[mi_][1], 0, 0, 0); \
    acc[mi_][2] = __builtin_amdgcn_mfma_f32_16x16x32_bf16(av_, bv2, acc[mi_][2], 0, 0, 0); \
    acc[mi_][3] = __builtin_amdgcn_mfma_f32_16x16x32_bf16(av_, bv3, acc[mi_][3], 0, 0, 0);

#define MFMA16(mh_)                                                           \
    __builtin_amdgcn_s_setprio(1);                                            \
    MFROW((mh_) * 4 + 0, av0);                                                \
    MFROW((mh_) * 4 + 1, av1);                                                \
    MFROW((mh_) * 4 + 2, av2);                                                \
    MFROW((mh_) * 4 + 3, av3);                                                \
    __builtin_amdgcn_s_setprio(0);

#define VMW(n_)  asm volatile("s_waitcnt vmcnt(" #n_ ")" ::: "memory")
#define LGKM0()  asm volatile("s_waitcnt lgkmcnt(0)" ::: "memory")
#define BAR()    __builtin_amdgcn_s_barrier()

    const int NT = K >> 6;   // K-tiles of 64 (NT=64 here); GROUP==128 => g=T>>1

    // ---- prologue: tiles 0 & 1 direct; prime A(1,1), B(1,0) in regs ----
    ARegs a00, a01, a10, A_f1;
    BRegs b00, b01, b11, B_i0;
    float sP0, sP1, zP0, zP1;            // sz for group of tile T+1 (g=0 here)
    sP0 = scale[(long long)nIdx[0] * G];
    sP1 = scale[(long long)nIdx[1] * G];
    zP0 = zero [(long long)nIdx[0] * G];
    zP1 = zero [(long long)nIdx[1] * G];
    LOAD_A(a00, 0, 0); LOAD_B(b00, 0, 0);
    LOAD_A(a01, 0, 1); LOAD_B(b01, 0, 1);
    LOAD_A(a10, 1, 0); LOAD_B(b11, 1, 1);
    VMW(0);
    WRITE_A(0, 0, a00); WRITE_B(0, 0, b00, sP0, zP0, sP1, zP1);
    WRITE_A(0, 1, a01); WRITE_B(0, 1, b01, sP0, zP0, sP1, zP1);
    WRITE_A(1, 0, a10); WRITE_B(1, 1, b11, sP0, zP0, sP1, zP1);
    LOAD_A(A_f1, 1, 1);                  // for T=0 P1 write
    LOAD_B(B_i0, 1, 0);                  // for T=0 P2 write
    LGKM0(); BAR();

    bf16x8 av0, av1, av2, av3, bv0, bv1, bv2, bv3;

    // ---- main loop: compute tile T; stage tile T+1 tail / T+2 head ----
    // P1: write A(T+1,kh1)  P2: write B(T+1,kh0)
    // P3: write A(T+2,kh0)  P4: write B(T+2,kh1)
    // Loads for a write issue exactly 2 phases earlier; vmcnt counts are
    // region-granular (4/8/4/4). lgkmcnt(0) before every barrier => all LDS
    // reads+writes of a phase complete before any wave enters the next.
#pragma unroll 2
    for (int T = 0; T <= NT - 3; ++T) {
        const int c = T & 1, cn = c ^ 1;
        ARegs A_f0n, A_f1n;
        BRegs B_i1n, B_i0n;
        float sN0, sN1, zN0, zN1;
        // P1: m0-3 x kk0
        READ_BV(c, 0);
        READ_AV(c, 0, 0);
        VMW(4);
        WRITE_A(cn, 1, A_f1);
        {
            const long long g2 = (T + 2) >> 1;
            sN0 = scale[(long long)nIdx[0] * G + g2];
            zN0 = zero [(long long)nIdx[0] * G + g2];
            sN1 = scale[(long long)nIdx[1] * G + g2];
            zN1 = zero [(long long)nIdx[1] * G + g2];
        }
        LOAD_A(A_f0n, T + 2, 0);
        LGKM0(); BAR();
        MFMA16(0);
        // P2: m4-7 x kk0 (bv reused)
        READ_AV(c, 0, 1);
        VMW(8);
        WRITE_B(cn, 0, B_i0, sP0, zP0, sP1, zP1);
        LOAD_B(B_i1n, T + 2, 1);
        LGKM0(); BAR();
        MFMA16(1);
        // P3: m0-3 x kk1
        READ_BV(c, 1);
        READ_AV(c, 1, 0);
        VMW(4);
        WRITE_A(c, 0, A_f0n);
        LOAD_A(A_f1n, T + 2, 1);
        LGKM0(); BAR();
        MFMA16(0);
        // P4: m4-7 x kk1
        READ_AV(c, 1, 1);
        VMW(4);
        WRITE_B(c, 1, B_i1n, sN0, zN0, sN1, zN1);
        LOAD_B(B_i0n, T + 2, 0);
        LGKM0(); BAR();
        MFMA16(1);
        // rotate pipeline registers
        A_f1 = A_f1n; B_i0 = B_i0n;
        sP0 = sN0; sP1 = sN1; zP0 = zN0; zP1 = zN1;
    }

    // ---- epilogue: tiles NT-2 and NT-1 ----
    {
        const int c2 = (NT - 2) & 1, c1 = (NT - 1) & 1;
        // epP1: write A(NT-1,kh1)
        READ_BV(c2, 0);
        READ_AV(c2, 0, 0);
        VMW(4);
        WRITE_A(c1, 1, A_f1);
        LGKM0(); BAR();
        MFMA16(0);
        // epP2: write B(NT-1,kh0)  (sP holds g(NT-1))
        READ_AV(c2, 0, 1);
        VMW(0);
        WRITE_B(c1, 0, B_i0, sP0, zP0, sP1, zP1);
        LGKM0(); BAR();
        MFMA16(1);
        // epP3/epP4: no writers remain -> no barriers needed
        READ_BV(c2, 1);
        READ_AV(c2, 1, 0);
        MFMA16(0);
        READ_AV(c2, 1, 1);
        MFMA16(1);
        // tile NT-1 (fully resident & visible)
        READ_BV(c1, 0);
        READ_AV(c1, 0, 0);
        MFMA16(0);
        READ_AV(c1, 0, 1);
        MFMA16(1);
        READ_BV(c1, 1);
        READ_AV(c1, 1, 0);
        MFMA16(0);
        READ_AV(c1, 1, 1);
        MFMA16(1);
    }

#undef LOAD_A
#undef LOAD_B
#undef WRITE_A
#undef WRITE_B
#undef READ_BV
#undef READ_AV
#undef MFROW
#undef MFMA16
#undef VMW
#undef LGKM0
#undef BAR

    // ---- C write: layout col=lane&15, row=quad*4+reg [m89-verified] ----
    const int colBase = blockN0 + wn * 64;
    const int rowBase = blockM0 + wm * 128;
    float biasf[4];
#pragma unroll
    for (int n = 0; n < 4; ++n)
        biasf[n] = bias[colBase + n * 16 + row16];

#pragma unroll
    for (int m = 0; m < 8; ++m) {
        const int row0 = rowBase + m * 16 + quad * 4;
#pragma unroll
        for (int n = 0; n < 4; ++n) {
            const int col = colBase + n * 16 + row16;
#pragma unroll
            for (int r = 0; r < 4; ++r) {
                C[(long long)(row0 + r) * N + col] = acc[m][n][r] + biasf[n];
            }
        }
    }
}

// ---------------- fallback: naive fused kernel (odd shapes) -----------------
#define BM 128
#define BN 128
#define BK 64

__global__ __launch_bounds__(256) void hqq_gemm_fused_f32(
    const float* __restrict__ A,
    const int*   __restrict__ Wq,
    const float* __restrict__ scale,
    const float* __restrict__ zero,
    const float* __restrict__ bias,
    float*       __restrict__ C,
    int M, int N, int K, int G, int GROUP)
{
    __shared__ unsigned short ldsA[BM * BK];
    __shared__ unsigned short ldsB[BN * BK];

    const int tid   = threadIdx.x;
    const int lane  = tid & 63;
    const int wave  = tid >> 6;
    const int waveM = wave >> 1;
    const int waveN = wave & 1;

    const int blockN0 = blockIdx.x * BN;
    const int blockM0 = blockIdx.y * BM;

    const int row16 = lane & 15;
    const int quad  = lane >> 4;

    f32x4 acc[4][4];
#pragma unroll
    for (int i = 0; i < 4; ++i)
#pragma unroll
        for (int j = 0; j < 4; ++j)
            acc[i][j] = (f32x4){0.f, 0.f, 0.f, 0.f};

    for (int k0 = 0; k0 < K; k0 += BK) {
        const int g = k0 / GROUP;
        int4 ra[4], rb[4];
#pragma unroll
        for (int c = 0; c < 4; ++c) {
            const int chunk = c * 256 + tid;
            const int row   = chunk >> 3;
            const int col   = (chunk & 7) * 8;

            const float* ap = A + (long long)(blockM0 + row) * K + k0 + col;
            const float4 a0 = *(const float4*)(ap);
            const float4 a1 = *(const float4*)(ap + 4);
            int4 da;
            da.x = pack_bf16x2(a0.x, a0.y);
            da.y = pack_bf16x2(a0.z, a0.w);
            da.z = pack_bf16x2(a1.x, a1.y);
            da.w = pack_bf16x2(a1.z, a1.w);
            ra[c] = da;

            const int n = blockN0 + row;
            const float s  = scale[(long long)n * G + g];
            const float z  = zero [(long long)n * G + g];
            const float mz = -z * s;
            const long long wb = (long long)n * K + k0 + col;
            const int4 q0 = *(const int4*)(Wq + wb);
            const int4 q1 = *(const int4*)(Wq + wb + 4);
            int4 db;
            db.x = pack_bf16x2((float)q0.x * s + mz, (float)q0.y * s + mz);
            db.y = pack_bf16x2((float)q0.z * s + mz, (float)q0.w * s + mz);
            db.z = pack_bf16x2((float)q1.x * s + mz, (float)q1.y * s + mz);
            db.w = pack_bf16x2((float)q1.z * s + mz, (float)q1.w * s + mz);
            rb[c] = db;
        }

        __syncthreads();
#pragma unroll
        for (int c = 0; c < 4; ++c) {
            const int chunk = c * 256 + tid;
            *(int4*)&ldsA[chunk * 8] = ra[c];
            *(int4*)&ldsB[chunk * 8] = rb[c];
        }
        __syncthreads();

#pragma unroll
        for (int kk = 0; kk < 2; ++kk) {
            const int kOff = kk * 32 + quad * 8;
            bf16x8 av[4], bv[4];
#pragma unroll
            for (int i = 0; i < 4; ++i)
                av[i] = *(const bf16x8*)&ldsA[(waveM * 64 + i * 16 + row16) * BK + kOff];
#pragma unroll
            for (int j = 0; j < 4; ++j)
                bv[j] = *(const bf16x8*)&ldsB[(waveN * 64 + j * 16 + row16) * BK + kOff];
#pragma unroll
            for (int i = 0; i < 4; ++i)
#pragma unroll
                for (int j = 0; j < 4; ++j)
                    acc[i][j] = __builtin_amdgcn_mfma_f32_16x16x32_bf16(
                        av[i], bv[j], acc[i][j], 0, 0, 0);
        }
    }

    const int colBase = blockN0 + waveN * 64;
    const int rowBase = blockM0 + waveM * 64;
    float biasf[4];
#pragma unroll
    for (int j = 0; j < 4; ++j)
        biasf[j] = bias[colBase + j * 16 + row16];

#pragma unroll
    for (int i = 0; i < 4; ++i) {
        const int row0 = rowBase + i * 16 + quad * 4;
#pragma unroll
        for (int j = 0; j < 4; ++j) {
            const int col = colBase + j * 16 + row16;
#pragma unroll
            for (int r = 0; r < 4; ++r) {
                C[(long long)(row0 + r) * N + col] = acc[i][j][r] + biasf[j];
            }
        }
    }
}

extern "C" void kernel_launch(void* const* d_in, const int* in_sizes, int n_in,
                              void* d_out, int out_size, void* d_ws, size_t ws_size,
                              hipStream_t stream) {
    (void)n_in; (void)out_size; (void)d_ws; (void)ws_size;

    const float* x     = (const float*)d_in[0];
    const int*   Wq    = (const int*)d_in[1];
    const float* scale = (const float*)d_in[2];
    const float* zero  = (const float*)d_in[3];
    const float* bias  = (const float*)d_in[4];
    float*       out   = (float*)d_out;

    const int N     = in_sizes[4];            // 4096
    const int G     = in_sizes[2] / N;        // 32
    const int K     = in_sizes[1] / N;        // 4096
    const int M     = in_sizes[0] / K;        // 4096 (B*S)
    const int GROUP = K / G;                  // 128

    const int nwg = (N >> 8) * (M >> 8);
    const int NT  = K >> 6;
    if ((M % 256) == 0 && (N % 256) == 0 && (K % 64) == 0 && NT >= 4 &&
        (nwg % 8) == 0 && GROUP == 128) {
        hqq_gemm256_fused<<<nwg, 512, 0, stream>>>(x, Wq, scale, zero, bias, out,
                                                   M, N, K, G);
    } else {
        dim3 grid(N / BN, M / BM);
        hqq_gemm_fused_f32<<<grid, 256, 0, stream>>>(x, Wq, scale, zero, bias, out,
                                                     M, N, K, G, GROUP);
    }
}

// Round 6
// 288.130 us; speedup vs baseline: 1.4439x; 1.4439x over previous
//
#include <hip/hip_runtime.h>
#include <hip/hip_bf16.h>

// HQQ 4-bit linear: out = x @ dequant(W_q)^T + bias
// M=B*S=4096, K=4096, N=4096, GROUP=128. Output FP32.
//
// Round 12: round-3 champion structure (256x256 tile, 4 phases/K-tile, ONE
// barrier per phase, global_load_lds staging, vmcnt(4)/tile) with the stage
// stream remapped so every stage targets a region last read >=2 phases
// earlier -- provably race-free with a single barrier (each phase's ds_reads
// are consumed by the MFMA right after that phase's barrier, hence complete
// before the next barrier; waves can skew at most one barrier segment):
//   P1 -> B(T+1,kh1)   P2 -> A(T+1,kh1)   (next read 5-6 phases later)
//   P3 -> B(T+2,kh0)   P4 -> A(T+2,kh0)   (last read 2 phases earlier)
// Overhead decomposition from round-11 experiment: fixed harness ~112us,
// prepass ~53us (floor 31us), GEMM the rest. Prepass byte-identical to
// round 3 for clean A/B on the GEMM schedule change.

typedef __bf16 bf16x8 __attribute__((ext_vector_type(8)));
typedef float f32x4 __attribute__((ext_vector_type(4)));

#define BM 128
#define BN 128
#define BK 64

static __device__ __forceinline__ int pack_bf16x2(float a, float b) {
    __hip_bfloat162 p = __float22bfloat162_rn(make_float2(a, b));
    int r;
    __builtin_memcpy(&r, &p, 4);
    return r;
}

// ---------------- fused pre-pass: convert x AND dequant Wq ------------------
__global__ __launch_bounds__(256) void prepass_kernel(
    const float* __restrict__ X, unsigned short* __restrict__ Ad,
    const int*   __restrict__ Wq,
    const float* __restrict__ scale,
    const float* __restrict__ zero,
    unsigned short* __restrict__ Wd,
    int aUnits, int wUnits, int K, int G, int GROUP)
{
    const int stride = gridDim.x * blockDim.x;
    const int t0     = blockIdx.x * blockDim.x + threadIdx.x;

    for (int u = t0; u < aUnits; u += stride) {
        const long long f = (long long)u * 8;
        const float4 a0 = *(const float4*)(X + f);
        const float4 a1 = *(const float4*)(X + f + 4);
        int4 d;
        d.x = pack_bf16x2(a0.x, a0.y);
        d.y = pack_bf16x2(a0.z, a0.w);
        d.z = pack_bf16x2(a1.x, a1.y);
        d.w = pack_bf16x2(a1.z, a1.w);
        *(int4*)(Ad + f) = d;
    }

    const int unitsPerRow = K >> 3;
    for (int u = t0; u < wUnits; u += stride) {
        const int n = u / unitsPerRow;
        const int k = (u - n * unitsPerRow) * 8;
        const int g = k / GROUP;
        const float s  = scale[(long long)n * G + g];
        const float z  = zero [(long long)n * G + g];
        const float mz = -z * s;

        const long long f = (long long)n * K + k;
        const int4 q0 = *(const int4*)(Wq + f);
        const int4 q1 = *(const int4*)(Wq + f + 4);
        int4 d;
        d.x = pack_bf16x2((float)q0.x * s + mz, (float)q0.y * s + mz);
        d.y = pack_bf16x2((float)q0.z * s + mz, (float)q0.w * s + mz);
        d.z = pack_bf16x2((float)q1.x * s + mz, (float)q1.y * s + mz);
        d.w = pack_bf16x2((float)q1.z * s + mz, (float)q1.w * s + mz);
        *(int4*)(Wd + f) = d;
    }
}

// ---------------- GEMM: 256x256 tile, 4-phase/K-tile, 1 barrier/phase -------
// 512 threads = 8 waves (2M x 4N); wave owns 128x64 of C = 8x4 fragments.
// LDS: [2 buf][2 khalf] subtiles of 256x32 bf16 (16KB each) per operand,
// 128 KiB total. Subtile packing (verified): phys row R (0..127) holds
// logical rows 2R,2R+1 x 4 chunks of 8 bf16; slot j of row R maps to
// ju=j^(R&7): logical row 2R+(ju>>2), col chunk ju&3. Writers pre-swizzle
// the global source (global_load_lds is linear); readers XOR the same term.
__global__ __launch_bounds__(512, 2) void gemm256_8ph(
    const unsigned short* __restrict__ A,     // bf16 bits [M,K]
    const unsigned short* __restrict__ Bw,    // bf16 bits [N,K]
    const float* __restrict__ bias,           // fp32 [N]
    float*       __restrict__ C,              // fp32 [M,N]
    int M, int N, int K)
{
    __shared__ unsigned short ldsA[2][2][8192];   // [buf][kh][256x32 packed]
    __shared__ unsigned short ldsB[2][2][8192];

    const int tid  = threadIdx.x;
    const int lane = tid & 63;
    const int wave = tid >> 6;     // 0..7
    const int wm   = wave >> 2;    // 0..1  (M half)
    const int wn   = wave & 3;     // 0..3  (N quarter)

    // XCD-bijective swizzle (nwg % 8 == 0 guaranteed by launcher).
    const int nwg  = (N >> 8) * (M >> 8);
    const int cpx  = nwg >> 3;
    const int bid  = blockIdx.x;
    const int wgid = (bid & 7) * cpx + (bid >> 3);
    const int bx   = wgid % (N >> 8);
    const int by   = wgid / (N >> 8);
    const int blockN0 = bx << 8;
    const int blockM0 = by << 8;

    // staging source offsets per load l (pre-swizzled global; LDS linear)
    long long gSrcA[2], gSrcB[2];
    int ldsDst[2];
#pragma unroll
    for (int l = 0; l < 2; ++l) {
        const int s  = l * 512 + tid;
        const int R  = s >> 3;
        const int j  = s & 7;
        const int ju = j ^ (R & 7);
        const int r  = 2 * R + (ju >> 2);
        const int cc = ju & 3;
        gSrcA[l] = (long long)(blockM0 + r) * K + cc * 8;
        gSrcB[l] = (long long)(blockN0 + r) * K + cc * 8;
        ldsDst[l] = (l * 512 + wave * 64) * 8;   // wave-uniform elem base
    }

    // fragment read offsets (elements within a 16KB subtile)
    const int row16 = lane & 15;
    const int quad  = lane >> 4;
    int offA[8], offB[4];
#pragma unroll
    for (int m = 0; m < 8; ++m) {
        const int r = wm * 128 + m * 16 + row16;
        const int R = r >> 1;
        const int j = (((r & 1) << 2) | quad) ^ (R & 7);
        offA[m] = R * 64 + j * 8;
    }
#pragma unroll
    for (int n = 0; n < 4; ++n) {
        const int r = wn * 64 + n * 16 + row16;
        const int R = r >> 1;
        const int j = (((r & 1) << 2) | quad) ^ (R & 7);
        offB[n] = R * 64 + j * 8;
    }

    f32x4 acc[8][4];
#pragma unroll
    for (int m = 0; m < 8; ++m)
#pragma unroll
        for (int n = 0; n < 4; ++n)
            acc[m][n] = (f32x4){0.f, 0.f, 0.f, 0.f};

#define STAGE_A(T_, KH_)                                                      \
    do {                                                                      \
        const int b_ = (T_) & 1;                                              \
        const long long ko_ = (long long)(T_) * 64 + (KH_) * 32;              \
        __builtin_amdgcn_global_load_lds(                                     \
            (const __attribute__((address_space(1))) unsigned int*)           \
                (A + gSrcA[0] + ko_),                                         \
            (__attribute__((address_space(3))) unsigned int*)                 \
                (&ldsA[b_][KH_][ldsDst[0]]), 16, 0, 0);                       \
        __builtin_amdgcn_global_load_lds(                                     \
            (const __attribute__((address_space(1))) unsigned int*)           \
                (A + gSrcA[1] + ko_),                                         \
            (__attribute__((address_space(3))) unsigned int*)                 \
                (&ldsA[b_][KH_][ldsDst[1]]), 16, 0, 0);                       \
    } while (0)

#define STAGE_B(T_, KH_)                                                      \
    do {                                                                      \
        const int b_ = (T_) & 1;                                              \
        const long long ko_ = (long long)(T_) * 64 + (KH_) * 32;              \
        __builtin_amdgcn_global_load_lds(                                     \
            (const __attribute__((address_space(1))) unsigned int*)           \
                (Bw + gSrcB[0] + ko_),                                        \
            (__attribute__((address_space(3))) unsigned int*)                 \
                (&ldsB[b_][KH_][ldsDst[0]]), 16, 0, 0);                       \
        __builtin_amdgcn_global_load_lds(                                     \
            (const __attribute__((address_space(1))) unsigned int*)           \
                (Bw + gSrcB[1] + ko_),                                        \
            (__attribute__((address_space(3))) unsigned int*)                 \
                (&ldsB[b_][KH_][ldsDst[1]]), 16, 0, 0);                       \
    } while (0)

#define READ_BV(c_, kk_)                                                      \
    bv0 = *(const bf16x8*)&ldsB[c_][kk_][offB[0]];                            \
    bv1 = *(const bf16x8*)&ldsB[c_][kk_][offB[1]];                            \
    bv2 = *(const bf16x8*)&ldsB[c_][kk_][offB[2]];                            \
    bv3 = *(const bf16x8*)&ldsB[c_][kk_][offB[3]];

#define READ_AV(c_, kk_, mh_)                                                 \
    av0 = *(const bf16x8*)&ldsA[c_][kk_][offA[(mh_) * 4 + 0]];                \
    av1 = *(const bf16x8*)&ldsA[c_][kk_][offA[(mh_) * 4 + 1]];                \
    av2 = *(const bf16x8*)&ldsA[c_][kk_][offA[(mh_) * 4 + 2]];                \
    av3 = *(const bf16x8*)&ldsA[c_][kk_][offA[(mh_) * 4 + 3]];

#define MFROW(mi_, av_)                                                       \
    acc[mi_][0] = __builtin_amdgcn_mfma_f32_16x16x32_bf16(av_, bv0, acc[mi_][0], 0, 0, 0); \
    acc[mi_][1] = __builtin_amdgcn_mfma_f32_16x16x32_bf16(av_, bv1, acc[mi_][1], 0, 0, 0); \
    acc[mi_][2] = __builtin_amdgcn_mfma_f32_16x16x32_bf16(av_, bv2, acc[mi_][2], 0, 0, 0); \
    acc[mi_][3] = __builtin_amdgcn_mfma_f32_16x16x32_bf16(av_, bv3, acc[mi_][3], 0, 0, 0);

#define MFMA16(mh_)                                                           \
    __builtin_amdgcn_s_setprio(1);                                            \
    MFROW((mh_) * 4 + 0, av0);                                                \
    MFROW((mh_) * 4 + 1, av1);                                                \
    MFROW((mh_) * 4 + 2, av2);                                                \
    MFROW((mh_) * 4 + 3, av3);                                                \
    __builtin_amdgcn_s_setprio(0);

#define BAR() __builtin_amdgcn_s_barrier()

    const int NT = K >> 6;   // K-tiles of 64; NT=64 here

    // ---- prologue: tile0 full (8 loads) + B(1,0),A(1,0) (4 loads);
    // vmcnt(4) retires tile0, leaves the tile1-kh0 pair in flight.
    STAGE_A(0, 0); STAGE_B(0, 0); STAGE_A(0, 1); STAGE_B(0, 1);
    STAGE_B(1, 0); STAGE_A(1, 0);
    asm volatile("s_waitcnt vmcnt(4)" ::: "memory");
    BAR();

    bf16x8 av0, av1, av2, av3, bv0, bv1, bv2, bv3;

    // ---- main loop ----
    // Stage targets are >=2 phases from their last read (race-free with one
    // barrier/phase); vmcnt(4) at P4 retires exactly through A(T+1,kh1) so
    // tile T+1 is fully resident (and barrier-visible) entering T+1.
#pragma unroll 2
    for (int T = 0; T <= NT - 3; ++T) {
        const int c = T & 1;
        // P1: m0-3 x kk0 ; stage B(T+1,kh1)
        READ_BV(c, 0);
        READ_AV(c, 0, 0);
        STAGE_B(T + 1, 1);
        BAR();
        MFMA16(0);
        // P2: m4-7 x kk0 (bv reused) ; stage A(T+1,kh1)
        READ_AV(c, 0, 1);
        STAGE_A(T + 1, 1);
        BAR();
        MFMA16(1);
        // P3: m0-3 x kk1 ; stage B(T+2,kh0) (last read @P1, 2 phases ago)
        READ_BV(c, 1);
        READ_AV(c, 1, 0);
        STAGE_B(T + 2, 0);
        BAR();
        MFMA16(0);
        // P4: m4-7 x kk1 ; stage A(T+2,kh0) (last read @P2, 2 phases ago)
        READ_AV(c, 1, 1);
        STAGE_A(T + 2, 0);
        asm volatile("s_waitcnt vmcnt(4)" ::: "memory");   // tile T+1 resident
        BAR();
        MFMA16(1);
    }

    // ---- epilogue: tile NT-2 (stage tile NT-1's kh1 units, then drain) ----
    {
        const int c2 = (NT - 2) & 1;
        READ_BV(c2, 0);
        READ_AV(c2, 0, 0);
        STAGE_B(NT - 1, 1);
        BAR();
        MFMA16(0);
        READ_AV(c2, 0, 1);
        STAGE_A(NT - 1, 1);
        BAR();
        MFMA16(1);
        READ_BV(c2, 1);
        READ_AV(c2, 1, 0);
        BAR();
        MFMA16(0);
        READ_AV(c2, 1, 1);
        asm volatile("s_waitcnt vmcnt(0)" ::: "memory");
        BAR();
        MFMA16(1);
    }
    // ---- tile NT-1: all resident & visible, no writers -> no barriers ----
    {
        const int c1 = (NT - 1) & 1;
        READ_BV(c1, 0); READ_AV(c1, 0, 0); MFMA16(0);
        READ_AV(c1, 0, 1); MFMA16(1);
        READ_BV(c1, 1); READ_AV(c1, 1, 0); MFMA16(0);
        READ_AV(c1, 1, 1); MFMA16(1);
    }

#undef STAGE_A
#undef STAGE_B
#undef READ_BV
#undef READ_AV
#undef MFROW
#undef MFMA16
#undef BAR

    // ---- C write: layout col=lane&15, row=quad*4+reg [m89-verified] ----
    const int colBase = blockN0 + wn * 64;
    const int rowBase = blockM0 + wm * 128;
    float biasf[4];
#pragma unroll
    for (int n = 0; n < 4; ++n)
        biasf[n] = bias[colBase + n * 16 + row16];

#pragma unroll
    for (int m = 0; m < 8; ++m) {
        const int row0 = rowBase + m * 16 + quad * 4;
#pragma unroll
        for (int n = 0; n < 4; ++n) {
            const int col = colBase + n * 16 + row16;
#pragma unroll
            for (int r = 0; r < 4; ++r) {
                C[(long long)(row0 + r) * N + col] = acc[m][n][r] + biasf[n];
            }
        }
    }
}

// ---------------- legacy 128x128 GEMM (fallback for odd shapes) -------------
__global__ __launch_bounds__(256, 2) void gemm_bf16_nt(
    const unsigned short* __restrict__ A,
    const unsigned short* __restrict__ Bw,
    const float* __restrict__ bias,
    float*       __restrict__ C,
    int M, int N, int K)
{
    __shared__ unsigned short ldsA[BM * BK];
    __shared__ unsigned short ldsB[BN * BK];

    const int tid   = threadIdx.x;
    const int lane  = tid & 63;
    const int wave  = tid >> 6;
    const int waveM = wave >> 1;
    const int waveN = wave & 1;

    const int blockN0 = blockIdx.x * BN;
    const int blockM0 = blockIdx.y * BM;

    const long long aBase = (long long)blockM0 * K;
    const long long bBase = (long long)blockN0 * K;

    const int rowInChunk = lane >> 3;
    const int colChunkSw = (lane & 7) ^ rowInChunk;
    const int col8       = colChunkSw * 8;

    f32x4 acc[4][4];
#pragma unroll
    for (int i = 0; i < 4; ++i)
#pragma unroll
        for (int j = 0; j < 4; ++j)
            acc[i][j] = (f32x4){0.f, 0.f, 0.f, 0.f};

    const int row16 = lane & 15;
    const int quad  = lane >> 4;
    const int sw    = row16 & 7;

    for (int k0 = 0; k0 < K; k0 += BK) {
        __syncthreads();
#pragma unroll
        for (int c = 0; c < 4; ++c) {
            const int chunk = (wave << 2) | c;
            const int row   = (chunk << 3) | rowInChunk;
            const unsigned short* gA = A  + aBase + (long long)row * K + k0 + col8;
            const unsigned short* gB = Bw + bBase + (long long)row * K + k0 + col8;
            __builtin_amdgcn_global_load_lds(
                (const __attribute__((address_space(1))) unsigned int*)gA,
                (__attribute__((address_space(3))) unsigned int*)&ldsA[chunk * 512],
                16, 0, 0);
            __builtin_amdgcn_global_load_lds(
                (const __attribute__((address_space(1))) unsigned int*)gB,
                (__attribute__((address_space(3))) unsigned int*)&ldsB[chunk * 512],
                16, 0, 0);
        }
        __syncthreads();

#pragma unroll
        for (int kk = 0; kk < 2; ++kk) {
            bf16x8 av[4], bv[4];
#pragma unroll
            for (int i = 0; i < 4; ++i) {
                const int r    = waveM * 64 + i * 16 + row16;
                const int slot = (kk * 4 + quad) ^ sw;
                av[i] = *(const bf16x8*)&ldsA[r * BK + slot * 8];
            }
#pragma unroll
            for (int j = 0; j < 4; ++j) {
                const int r    = waveN * 64 + j * 16 + row16;
                const int slot = (kk * 4 + quad) ^ sw;
                bv[j] = *(const bf16x8*)&ldsB[r * BK + slot * 8];
            }
#pragma unroll
            for (int i = 0; i < 4; ++i)
#pragma unroll
                for (int j = 0; j < 4; ++j)
                    acc[i][j] = __builtin_amdgcn_mfma_f32_16x16x32_bf16(
                        av[i], bv[j], acc[i][j], 0, 0, 0);
        }
    }

    const int colBase = blockN0 + waveN * 64;
    const int rowBase = blockM0 + waveM * 64;
    float biasf[4];
#pragma unroll
    for (int j = 0; j < 4; ++j)
        biasf[j] = bias[colBase + j * 16 + row16];

#pragma unroll
    for (int i = 0; i < 4; ++i) {
        const int row0 = rowBase + i * 16 + quad * 4;
#pragma unroll
        for (int j = 0; j < 4; ++j) {
            const int col = colBase + j * 16 + row16;
#pragma unroll
            for (int r = 0; r < 4; ++r) {
                C[(long long)(row0 + r) * N + col] = acc[i][j][r] + biasf[j];
            }
        }
    }
}

// ---------------- fallback: fused kernel (no workspace) ---------------------
__global__ __launch_bounds__(256) void hqq_gemm_fused_f32(
    const float* __restrict__ A,
    const int*   __restrict__ Wq,
    const float* __restrict__ scale,
    const float* __restrict__ zero,
    const float* __restrict__ bias,
    float*       __restrict__ C,
    int M, int N, int K, int G, int GROUP)
{
    __shared__ unsigned short ldsA[BM * BK];
    __shared__ unsigned short ldsB[BN * BK];

    const int tid   = threadIdx.x;
    const int lane  = tid & 63;
    const int wave  = tid >> 6;
    const int waveM = wave >> 1;
    const int waveN = wave & 1;

    const int blockN0 = blockIdx.x * BN;
    const int blockM0 = blockIdx.y * BM;

    const int row16 = lane & 15;
    const int quad  = lane >> 4;

    f32x4 acc[4][4];
#pragma unroll
    for (int i = 0; i < 4; ++i)
#pragma unroll
        for (int j = 0; j < 4; ++j)
            acc[i][j] = (f32x4){0.f, 0.f, 0.f, 0.f};

    for (int k0 = 0; k0 < K; k0 += BK) {
        const int g = k0 / GROUP;
        int4 ra[4], rb[4];
#pragma unroll
        for (int c = 0; c < 4; ++c) {
            const int chunk = c * 256 + tid;
            const int row   = chunk >> 3;
            const int col   = (chunk & 7) * 8;

            const float* ap = A + (long long)(blockM0 + row) * K + k0 + col;
            const float4 a0 = *(const float4*)(ap);
            const float4 a1 = *(const float4*)(ap + 4);
            int4 da;
            da.x = pack_bf16x2(a0.x, a0.y);
            da.y = pack_bf16x2(a0.z, a0.w);
            da.z = pack_bf16x2(a1.x, a1.y);
            da.w = pack_bf16x2(a1.z, a1.w);
            ra[c] = da;

            const int n = blockN0 + row;
            const float s  = scale[(long long)n * G + g];
            const float z  = zero [(long long)n * G + g];
            const float mz = -z * s;
            const long long wb = (long long)n * K + k0 + col;
            const int4 q0 = *(const int4*)(Wq + wb);
            const int4 q1 = *(const int4*)(Wq + wb + 4);
            int4 db;
            db.x = pack_bf16x2((float)q0.x * s + mz, (float)q0.y * s + mz);
            db.y = pack_bf16x2((float)q0.z * s + mz, (float)q0.w * s + mz);
            db.z = pack_bf16x2((float)q1.x * s + mz, (float)q1.y * s + mz);
            db.w = pack_bf16x2((float)q1.z * s + mz, (float)q1.w * s + mz);
            rb[c] = db;
        }

        __syncthreads();
#pragma unroll
        for (int c = 0; c < 4; ++c) {
            const int chunk = c * 256 + tid;
            *(int4*)&ldsA[chunk * 8] = ra[c];
            *(int4*)&ldsB[chunk * 8] = rb[c];
        }
        __syncthreads();

#pragma unroll
        for (int kk = 0; kk < 2; ++kk) {
            const int kOff = kk * 32 + quad * 8;
            bf16x8 av[4], bv[4];
#pragma unroll
            for (int i = 0; i < 4; ++i)
                av[i] = *(const bf16x8*)&ldsA[(waveM * 64 + i * 16 + row16) * BK + kOff];
#pragma unroll
            for (int j = 0; j < 4; ++j)
                bv[j] = *(const bf16x8*)&ldsB[(waveN * 64 + j * 16 + row16) * BK + kOff];
#pragma unroll
            for (int i = 0; i < 4; ++i)
#pragma unroll
                for (int j = 0; j < 4; ++j)
                    acc[i][j] = __builtin_amdgcn_mfma_f32_16x16x32_bf16(
                        av[i], bv[j], acc[i][j], 0, 0, 0);
        }
    }

    const int colBase = blockN0 + waveN * 64;
    const int rowBase = blockM0 + waveM * 64;
    float biasf[4];
#pragma unroll
    for (int j = 0; j < 4; ++j)
        biasf[j] = bias[colBase + j * 16 + row16];

#pragma unroll
    for (int i = 0; i < 4; ++i) {
        const int row0 = rowBase + i * 16 + quad * 4;
#pragma unroll
        for (int j = 0; j < 4; ++j) {
            const int col = colBase + j * 16 + row16;
#pragma unroll
            for (int r = 0; r < 4; ++r) {
                C[(long long)(row0 + r) * N + col] = acc[i][j][r] + biasf[j];
            }
        }
    }
}

extern "C" void kernel_launch(void* const* d_in, const int* in_sizes, int n_in,
                              void* d_out, int out_size, void* d_ws, size_t ws_size,
                              hipStream_t stream) {
    (void)n_in; (void)out_size;

    const float* x     = (const float*)d_in[0];
    const int*   Wq    = (const int*)d_in[1];
    const float* scale = (const float*)d_in[2];
    const float* zero  = (const float*)d_in[3];
    const float* bias  = (const float*)d_in[4];
    float*       out   = (float*)d_out;

    const int N     = in_sizes[4];            // 4096
    const int G     = in_sizes[2] / N;        // 32
    const int K     = in_sizes[1] / N;        // 4096
    const int M     = in_sizes[0] / K;        // 4096 (B*S)
    const int GROUP = K / G;                  // 128

    const size_t needWs = (size_t)N * K * 2 + (size_t)M * K * 2;  // 64 MB

    if (ws_size >= needWs) {
        unsigned short* Wd = (unsigned short*)d_ws;                        // [N,K] bf16
        unsigned short* Ad = (unsigned short*)((char*)d_ws + (size_t)N * K * 2);  // [M,K] bf16

        const int aUnits = (int)((long long)M * K / 8);
        const int wUnits = (int)((long long)N * K / 8);
        prepass_kernel<<<2048, 256, 0, stream>>>(x, Ad, Wq, scale, zero, Wd,
                                                 aUnits, wUnits, K, G, GROUP);

        const int nwg = (N >> 8) * (M >> 8);
        const int NT  = K >> 6;
        if ((M % 256) == 0 && (N % 256) == 0 && (K % 64) == 0 && NT >= 4 &&
            (nwg % 8) == 0) {
            gemm256_8ph<<<nwg, 512, 0, stream>>>(Ad, Wd, bias, out, M, N, K);
        } else {
            dim3 grid(N / BN, M / BM);
            gemm_bf16_nt<<<grid, 256, 0, stream>>>(Ad, Wd, bias, out, M, N, K);
        }
    } else {
        dim3 grid(N / BN, M / BM);
        hqq_gemm_fused_f32<<<grid, 256, 0, stream>>>(x, Wq, scale, zero, bias, out,
                                                     M, N, K, G, GROUP);
    }
}